// Round 1
// baseline (910.332 us; speedup 1.0000x reference)
//
#include <hip/hip_runtime.h>
#include <math.h>

#define BATCH 64
#define N 1024
#define R 16                 // rows per block in the fused pass kernel
#define CHUNKS (N / R)       // 64 row-stripes per batch
#define NEG_INF (-3.402823466e+38f)

__device__ __forceinline__ float inv_tau() { return 1.0f / 0.01f; }

__global__ __launch_bounds__(256) void zero_kernel(float* __restrict__ p, int n) {
    int i = blockIdx.x * 256 + threadIdx.x;
    if (i < n) p[i] = 0.0f;
}

// Fused pass: for its 16-row stripe, compute A_i = LSE_j(x*invtau - B_j),
// then column partials (m,s) of (x*invtau - A_i) over the stripe.
__global__ __launch_bounds__(256) void rowcol_kernel(
    const float* __restrict__ x, const float* __restrict__ bvec,
    float* __restrict__ avec, float* __restrict__ pm, float* __restrict__ ps)
{
    const int blk   = blockIdx.x;
    const int batch = blk / CHUNKS;
    const int chunk = blk % CHUNKS;
    const float* xb = x + (size_t)batch * N * N + (size_t)chunk * R * N;
    const int tid  = threadIdx.x;
    const int wave = tid >> 6;
    const int lane = tid & 63;

    __shared__ float A_s[R];

    // B values for this lane's columns: col = p*256 + lane*4 + c
    const float4* bv4 = (const float4*)(bvec + (size_t)batch * N);
    float4 bv[4];
    #pragma unroll
    for (int p = 0; p < 4; ++p) bv[p] = bv4[p * 64 + lane];

    const float it = inv_tau();

    // ---- Phase A: each wave handles 4 rows ----
    #pragma unroll
    for (int q = 0; q < 4; ++q) {
        const int r = wave * 4 + q;
        const float4* row4 = (const float4*)(xb + (size_t)r * N);
        float4 xv[4];
        #pragma unroll
        for (int p = 0; p < 4; ++p) xv[p] = row4[p * 64 + lane];

        float v[16];
        float m = NEG_INF;
        #pragma unroll
        for (int p = 0; p < 4; ++p) {
            v[p * 4 + 0] = xv[p].x * it - bv[p].x;
            v[p * 4 + 1] = xv[p].y * it - bv[p].y;
            v[p * 4 + 2] = xv[p].z * it - bv[p].z;
            v[p * 4 + 3] = xv[p].w * it - bv[p].w;
        }
        #pragma unroll
        for (int e = 0; e < 16; ++e) m = fmaxf(m, v[e]);
        #pragma unroll
        for (int off = 32; off >= 1; off >>= 1)
            m = fmaxf(m, __shfl_xor(m, off, 64));

        float s = 0.0f;
        #pragma unroll
        for (int e = 0; e < 16; ++e) s += __expf(v[e] - m);
        #pragma unroll
        for (int off = 32; off >= 1; off >>= 1)
            s += __shfl_xor(s, off, 64);

        if (lane == 0) {
            float A = m + __logf(s);
            avec[(size_t)batch * N + (size_t)chunk * R + r] = A;
            A_s[r] = A;
        }
    }
    __syncthreads();

    // ---- Phase B: thread t owns columns 4t..4t+3, reduce over 16 rows ----
    // Re-read the stripe (L1/L2-hot; 64 KB/block).
    float4 xr[R];
    #pragma unroll
    for (int i = 0; i < R; ++i)
        xr[i] = ((const float4*)(xb + (size_t)i * N))[tid];

    float4 mc; mc.x = mc.y = mc.z = mc.w = NEG_INF;
    #pragma unroll
    for (int i = 0; i < R; ++i) {
        float a = A_s[i];
        mc.x = fmaxf(mc.x, xr[i].x * it - a);
        mc.y = fmaxf(mc.y, xr[i].y * it - a);
        mc.z = fmaxf(mc.z, xr[i].z * it - a);
        mc.w = fmaxf(mc.w, xr[i].w * it - a);
    }
    float4 sc; sc.x = sc.y = sc.z = sc.w = 0.0f;
    #pragma unroll
    for (int i = 0; i < R; ++i) {
        float a = A_s[i];
        sc.x += __expf(xr[i].x * it - a - mc.x);
        sc.y += __expf(xr[i].y * it - a - mc.y);
        sc.z += __expf(xr[i].z * it - a - mc.z);
        sc.w += __expf(xr[i].w * it - a - mc.w);
    }
    const size_t pbase = ((size_t)batch * CHUNKS + chunk) * N;
    ((float4*)(pm + pbase))[tid] = mc;
    ((float4*)(ps + pbase))[tid] = sc;
}

// Fold 64 stripe partials per column into B_j = LSE_i(x*invtau - A_i).
__global__ __launch_bounds__(256) void combine_kernel(
    const float* __restrict__ pm, const float* __restrict__ ps,
    float* __restrict__ bvec)
{
    const int idx   = blockIdx.x * 256 + threadIdx.x;  // 0..BATCH*N-1
    const int batch = idx >> 10;
    const int j     = idx & (N - 1);
    const float* pmb = pm + (size_t)batch * CHUNKS * N + j;
    const float* psb = ps + (size_t)batch * CHUNKS * N + j;

    float m = NEG_INF;
    #pragma unroll 8
    for (int c = 0; c < CHUNKS; ++c) m = fmaxf(m, pmb[(size_t)c * N]);
    float s = 0.0f;
    #pragma unroll 8
    for (int c = 0; c < CHUNKS; ++c)
        s += psb[(size_t)c * N] * __expf(pmb[(size_t)c * N] - m);
    bvec[idx] = m + __logf(s);
}

// out = exp(x*invtau - A_i - B_j) + 1e-6
__global__ __launch_bounds__(256) void output_kernel(
    const float* __restrict__ x, const float* __restrict__ avec,
    const float* __restrict__ bvec, float* __restrict__ out)
{
    const int row   = blockIdx.x;      // batch*N + i
    const int batch = row >> 10;
    const float A   = avec[row];
    const int t     = threadIdx.x;
    const float it  = inv_tau();

    float4 xv = ((const float4*)(x + (size_t)row * N))[t];
    float4 bv = ((const float4*)(bvec + (size_t)batch * N))[t];
    float4 o;
    o.x = __expf(xv.x * it - A - bv.x) + 1e-6f;
    o.y = __expf(xv.y * it - A - bv.y) + 1e-6f;
    o.z = __expf(xv.z * it - A - bv.z) + 1e-6f;
    o.w = __expf(xv.w * it - A - bv.w) + 1e-6f;
    ((float4*)(out + (size_t)row * N))[t] = o;
}

extern "C" void kernel_launch(void* const* d_in, const int* in_sizes, int n_in,
                              void* d_out, int out_size, void* d_ws, size_t ws_size,
                              hipStream_t stream) {
    const float* x = (const float*)d_in[0];
    float* out = (float*)d_out;
    char* ws = (char*)d_ws;

    float* avec = (float*)ws;                         // BATCH*N f32
    float* bvec = avec + (size_t)BATCH * N;           // BATCH*N f32
    const size_t small_bytes = 2ull * BATCH * N * sizeof(float);      // 512 KB
    const size_t pelems      = (size_t)BATCH * CHUNKS * N;            // 4.2M
    const size_t pbytes      = pelems * sizeof(float);                // ~16.8 MB

    float* pm;
    float* ps;
    if (ws_size >= small_bytes + 2 * pbytes) {
        pm = (float*)(ws + small_bytes);
        ps = pm + pelems;
    } else {
        // Park partials in d_out: fully consumed by combine_kernel before
        // output_kernel overwrites d_out. 2*16.8 MB << 268 MB.
        pm = out;
        ps = out + pelems;
    }

    zero_kernel<<<(BATCH * N) / 256, 256, 0, stream>>>(bvec, BATCH * N);
    for (int iter = 0; iter < 5; ++iter) {
        rowcol_kernel<<<BATCH * CHUNKS, 256, 0, stream>>>(x, bvec, avec, pm, ps);
        combine_kernel<<<(BATCH * N) / 256, 256, 0, stream>>>(pm, ps, bvec);
    }
    output_kernel<<<BATCH * N, 256, 0, stream>>>(x, avec, bvec, out);
}

// Round 2
// 795.896 us; speedup vs baseline: 1.1438x; 1.1438x over previous
//
#include <hip/hip_runtime.h>
#include <math.h>

#define BATCH 64
#define N 1024
#define R 16                 // rows per block (4 waves x 4 rows, held in registers)
#define CHUNKS (N / R)       // 64 row-stripes per batch
#define NEG_INF (-3.402823466e+38f)
#define INV_TAU 100.0f

__global__ __launch_bounds__(256) void zero_kernel(float* __restrict__ p, int n) {
    int i = blockIdx.x * 256 + threadIdx.x;
    if (i < n) p[i] = 0.0f;
}

// One fused pass per iteration, reading x exactly ONCE:
//   A_i = LSE_j(x*invtau - B_j)   (row pass, per wave, 4 rows in registers)
//   column partials (m,s) of (x*invtau - A_i) over the 16-row stripe
// Cross-wave column merge via padded LDS.
__global__ __launch_bounds__(256) void rowcol_kernel(
    const float* __restrict__ x, const float* __restrict__ bvec,
    float* __restrict__ avec, float* __restrict__ pm, float* __restrict__ ps)
{
    const int blk   = blockIdx.x;
    const int batch = blk >> 6;          // / CHUNKS
    const int chunk = blk & (CHUNKS - 1);
    const float* xb = x + (size_t)batch * N * N + (size_t)chunk * R * N;
    const int tid  = threadIdx.x;
    const int wave = tid >> 6;
    const int lane = tid & 63;

    // stride 17 pad: lane*17 mod 32 spreads across banks (2-way max = free)
    __shared__ float lds_m[4][64][17];
    __shared__ float lds_s[4][64][17];

    // B for this lane's 16 columns: col = p*256 + lane*4 + c, e = p*4+c
    const float4* bv4 = (const float4*)(bvec + (size_t)batch * N);
    float bvf[16];
    #pragma unroll
    for (int p = 0; p < 4; ++p) {
        float4 b = bv4[p * 64 + lane];
        bvf[p*4+0] = b.x; bvf[p*4+1] = b.y; bvf[p*4+2] = b.z; bvf[p*4+3] = b.w;
    }

    // v[q][e] = x*invtau - B  for row wave*4+q, this lane's 16 columns
    float v[4][16];
    float A[4];

    #pragma unroll
    for (int q = 0; q < 4; ++q) {
        const int r = wave * 4 + q;
        const float4* row4 = (const float4*)(xb + (size_t)r * N);
        #pragma unroll
        for (int p = 0; p < 4; ++p) {
            float4 xv = row4[p * 64 + lane];
            v[q][p*4+0] = xv.x * INV_TAU - bvf[p*4+0];
            v[q][p*4+1] = xv.y * INV_TAU - bvf[p*4+1];
            v[q][p*4+2] = xv.z * INV_TAU - bvf[p*4+2];
            v[q][p*4+3] = xv.w * INV_TAU - bvf[p*4+3];
        }
        float m = NEG_INF;
        #pragma unroll
        for (int e = 0; e < 16; ++e) m = fmaxf(m, v[q][e]);
        #pragma unroll
        for (int off = 32; off >= 1; off >>= 1)
            m = fmaxf(m, __shfl_xor(m, off, 64));
        float s = 0.0f;
        #pragma unroll
        for (int e = 0; e < 16; ++e) s += __expf(v[q][e] - m);
        #pragma unroll
        for (int off = 32; off >= 1; off >>= 1)
            s += __shfl_xor(s, off, 64);
        A[q] = m + __logf(s);                     // all lanes have it
        if (lane == 0)
            avec[(size_t)batch * N + (size_t)chunk * R + r] = A[q];
    }

    // Per-wave column partials over its 4 rows. Column value z = (v - A) + B.
    // Track t = v - A; final partial max = max_t + B, sum unchanged.
    #pragma unroll
    for (int e = 0; e < 16; ++e) {
        float t0 = v[0][e] - A[0];
        float t1 = v[1][e] - A[1];
        float t2 = v[2][e] - A[2];
        float t3 = v[3][e] - A[3];
        float m0 = fmaxf(fmaxf(t0, t1), fmaxf(t2, t3));
        float s0 = __expf(t0 - m0) + __expf(t1 - m0) +
                   __expf(t2 - m0) + __expf(t3 - m0);
        lds_m[wave][lane][e] = m0 + bvf[e];
        lds_s[wave][lane][e] = s0;
    }
    __syncthreads();

    // Merge 4 waves; thread t owns columns j = 4t..4t+3:
    //   l = t&63, e = (t>>6)*4 + c   (verified bijection)
    const int l = tid & 63;
    const int p = tid >> 6;
    float mo[4], so[4];
    #pragma unroll
    for (int c = 0; c < 4; ++c) {
        const int e = p * 4 + c;
        float m = lds_m[0][l][e];
        m = fmaxf(m, lds_m[1][l][e]);
        m = fmaxf(m, lds_m[2][l][e]);
        m = fmaxf(m, lds_m[3][l][e]);
        float s = 0.0f;
        #pragma unroll
        for (int w = 0; w < 4; ++w)
            s += lds_s[w][l][e] * __expf(lds_m[w][l][e] - m);
        mo[c] = m; so[c] = s;
    }
    const size_t pbase = ((size_t)batch * CHUNKS + chunk) * N;
    ((float4*)(pm + pbase))[tid] = make_float4(mo[0], mo[1], mo[2], mo[3]);
    ((float4*)(ps + pbase))[tid] = make_float4(so[0], so[1], so[2], so[3]);
}

// Fold 64 stripe partials per column into B_j = LSE_i(x*invtau - A_i).
__global__ __launch_bounds__(256) void combine_kernel(
    const float* __restrict__ pm, const float* __restrict__ ps,
    float* __restrict__ bvec)
{
    const int idx   = blockIdx.x * 256 + threadIdx.x;  // 0..BATCH*N-1
    const int batch = idx >> 10;
    const int j     = idx & (N - 1);
    const float* pmb = pm + (size_t)batch * CHUNKS * N + j;
    const float* psb = ps + (size_t)batch * CHUNKS * N + j;

    float m = NEG_INF;
    #pragma unroll 8
    for (int c = 0; c < CHUNKS; ++c) m = fmaxf(m, pmb[(size_t)c * N]);
    float s = 0.0f;
    #pragma unroll 8
    for (int c = 0; c < CHUNKS; ++c)
        s += psb[(size_t)c * N] * __expf(pmb[(size_t)c * N] - m);
    bvec[idx] = m + __logf(s);
}

// out = exp(x*invtau - A_i - B_j) + 1e-6
__global__ __launch_bounds__(256) void output_kernel(
    const float* __restrict__ x, const float* __restrict__ avec,
    const float* __restrict__ bvec, float* __restrict__ out)
{
    const int row   = blockIdx.x;      // batch*N + i
    const int batch = row >> 10;
    const float A   = avec[row];
    const int t     = threadIdx.x;

    float4 xv = ((const float4*)(x + (size_t)row * N))[t];
    float4 bv = ((const float4*)(bvec + (size_t)batch * N))[t];
    float4 o;
    o.x = __expf(xv.x * INV_TAU - A - bv.x) + 1e-6f;
    o.y = __expf(xv.y * INV_TAU - A - bv.y) + 1e-6f;
    o.z = __expf(xv.z * INV_TAU - A - bv.z) + 1e-6f;
    o.w = __expf(xv.w * INV_TAU - A - bv.w) + 1e-6f;
    ((float4*)(out + (size_t)row * N))[t] = o;
}

extern "C" void kernel_launch(void* const* d_in, const int* in_sizes, int n_in,
                              void* d_out, int out_size, void* d_ws, size_t ws_size,
                              hipStream_t stream) {
    const float* x = (const float*)d_in[0];
    float* out = (float*)d_out;
    char* ws = (char*)d_ws;

    float* avec = (float*)ws;                         // BATCH*N f32
    float* bvec = avec + (size_t)BATCH * N;           // BATCH*N f32
    const size_t small_bytes = 2ull * BATCH * N * sizeof(float);      // 512 KB
    const size_t pelems      = (size_t)BATCH * CHUNKS * N;            // 4.2M
    const size_t pbytes      = pelems * sizeof(float);                // ~16.8 MB

    float* pm;
    float* ps;
    if (ws_size >= small_bytes + 2 * pbytes) {
        pm = (float*)(ws + small_bytes);
        ps = pm + pelems;
    } else {
        // Park partials in d_out: fully consumed by combine_kernel before
        // output_kernel overwrites d_out.
        pm = out;
        ps = out + pelems;
    }

    zero_kernel<<<(BATCH * N) / 256, 256, 0, stream>>>(bvec, BATCH * N);
    for (int iter = 0; iter < 5; ++iter) {
        rowcol_kernel<<<BATCH * CHUNKS, 256, 0, stream>>>(x, bvec, avec, pm, ps);
        combine_kernel<<<(BATCH * N) / 256, 256, 0, stream>>>(pm, ps, bvec);
    }
    output_kernel<<<BATCH * N, 256, 0, stream>>>(x, avec, bvec, out);
}